// Round 1
// baseline (408.083 us; speedup 1.0000x reference)
//
#include <hip/hip_runtime.h>
#include <cstdint>
#include <cstddef>

#define B_   2
#define S_   2048
#define H_   2048
#define NH_  16
#define HD_  128
#define MM_  (B_ * S_)          /* 4096 rows of x */
#define K_   H_                 /* 2048 reduction dim for projections */
#define SCALE_F 0.08838834764831845f

typedef __bf16 bf16_t;
typedef __attribute__((ext_vector_type(8))) __bf16 bf16x8;
typedef __attribute__((ext_vector_type(4))) float  f32x4;
typedef __attribute__((ext_vector_type(4))) float  floatx4;

static __device__ __forceinline__ f32x4 mfma_16x16x32(bf16x8 a, bf16x8 b, f32x4 c) {
  return __builtin_amdgcn_mfma_f32_16x16x32_bf16(a, b, c, 0, 0, 0);
}

static __device__ __forceinline__ void gl2lds16(const bf16_t* g, bf16_t* l) {
  __builtin_amdgcn_global_load_lds(
      (const __attribute__((address_space(1))) void*)g,
      (__attribute__((address_space(3))) void*)l, 16, 0, 0);
}

// ---------------------------------------------------------------- fp32->bf16
__global__ void cvt_f32_bf16(const float* __restrict__ in, bf16_t* __restrict__ out, int n8) {
  int i = blockIdx.x * blockDim.x + threadIdx.x;
  const int stride = gridDim.x * blockDim.x;
  for (; i < n8; i += stride) {
    const floatx4* p = (const floatx4*)(in + (size_t)i * 8);
    floatx4 a = p[0], b = p[1];
    bf16x8 o;
    o[0] = (bf16_t)a.x; o[1] = (bf16_t)a.y; o[2] = (bf16_t)a.z; o[3] = (bf16_t)a.w;
    o[4] = (bf16_t)b.x; o[5] = (bf16_t)b.y; o[6] = (bf16_t)b.z; o[7] = (bf16_t)b.w;
    *(bf16x8*)(out + (size_t)i * 8) = o;
  }
}

// ------------------------------------------------------- GEMM C = A * B^T + b
// A: [M,K] bf16 row-major.  B: [N,K] bf16 row-major (i.e. already transposed).
// MODE 0: fused QKV. grid.y in [0,48): wsel = y>>4 picks W/bias/dst; epilogue
//         writes bf16 into head-major [B*NH, S, HD].
// MODE 1: O-projection. epilogue writes fp32 [M, H] + bias.
template <int MODE>
__global__ __launch_bounds__(256) void gemm_bt(
    const bf16_t* __restrict__ A,
    const bf16_t* __restrict__ W0, const bf16_t* __restrict__ W1, const bf16_t* __restrict__ W2,
    const float* __restrict__ bias0, const float* __restrict__ bias1, const float* __restrict__ bias2,
    bf16_t* __restrict__ dq, bf16_t* __restrict__ dk, bf16_t* __restrict__ dv,
    float* __restrict__ outf)
{
  __shared__ __align__(16) bf16_t Ash[128 * 32];
  __shared__ __align__(16) bf16_t Bsh[128 * 32];

  const int t = threadIdx.x;
  const int lane = t & 63;
  const int wid  = t >> 6;
  const int wm = wid >> 1, wn = wid & 1;

  const int bm = blockIdx.x * 128;
  int bn;
  const bf16_t* Bw;
  const float*  bias;
  bf16_t* dsth = nullptr;
  if constexpr (MODE == 0) {
    const int wsel = blockIdx.y >> 4;
    bn   = (blockIdx.y & 15) * 128;
    Bw   = (wsel == 0) ? W0 : ((wsel == 1) ? W1 : W2);
    bias = (wsel == 0) ? bias0 : ((wsel == 1) ? bias1 : bias2);
    dsth = (wsel == 0) ? dq : ((wsel == 1) ? dk : dv);
  } else {
    bn = blockIdx.y * 128;
    Bw = W0; bias = bias0;
  }

  // staging: thread t covers 16B at row t>>2, col (t&3)*8 (and +64 rows)
  const bf16_t* gA = A  + (size_t)(bm + (t >> 2)) * K_ + (t & 3) * 8;
  const bf16_t* gB = Bw + (size_t)(bn + (t >> 2)) * K_ + (t & 3) * 8;
  bf16_t* lA = Ash + wid * 512;   // wave-uniform LDS base, lanes append *16B
  bf16_t* lB = Bsh + wid * 512;

  f32x4 acc[4][4] = {};

  #pragma unroll 1
  for (int k0 = 0; k0 < K_; k0 += 32) {
    gl2lds16(gA + k0,                    lA);
    gl2lds16(gA + k0 + (size_t)64 * K_,  lA + 2048);
    gl2lds16(gB + k0,                    lB);
    gl2lds16(gB + k0 + (size_t)64 * K_,  lB + 2048);
    __syncthreads();

    bf16x8 af[4], bf[4];
    #pragma unroll
    for (int i = 0; i < 4; ++i) {
      af[i] = *(const bf16x8*)&Ash[(wm * 64 + i * 16 + (lane & 15)) * 32 + (lane >> 4) * 8];
      bf[i] = *(const bf16x8*)&Bsh[(wn * 64 + i * 16 + (lane & 15)) * 32 + (lane >> 4) * 8];
    }
    #pragma unroll
    for (int i = 0; i < 4; ++i)
      #pragma unroll
      for (int j = 0; j < 4; ++j)
        acc[i][j] = mfma_16x16x32(af[i], bf[j], acc[i][j]);
    __syncthreads();
  }

  // epilogue. C/D frag: col = lane&15, row = (lane>>4)*4 + r  [m89/m91]
  const int row0 = bm + wm * 64 + (lane >> 4) * 4;
  const int col0 = bn + wn * 64 + (lane & 15);
  #pragma unroll
  for (int j = 0; j < 4; ++j) {
    const int col = col0 + j * 16;
    const float bv = bias[col];
    #pragma unroll
    for (int i = 0; i < 4; ++i) {
      #pragma unroll
      for (int r = 0; r < 4; ++r) {
        const int row = row0 + i * 16 + r;
        const float v = acc[i][j][r] + bv;
        if constexpr (MODE == 0) {
          const int bb = row >> 11, ss = row & (S_ - 1);
          const int hh = col >> 7,  dd = col & (HD_ - 1);
          dsth[((((size_t)bb * NH_) + hh) * S_ + ss) * HD_ + dd] = (bf16_t)v;
        } else {
          outf[(size_t)row * H_ + col] = v;
        }
      }
    }
  }
}

// ------------------------------------------------------------ flash attention
// grid: (S/128 q-tiles, B*NH heads). 4 waves x 32 q-rows. KV tile = 64.
// V^T staged with kk-XOR swizzle so transpose-writes and B-frag reads are
// near-conflict-free without breaking ds_read_b128 alignment.
#define KVB 64
#define VT_IDX(d, kkx) ((d) * 72 + ((kkx) ^ (((((d) >> 3) & 7)) << 3)))

__global__ __launch_bounds__(256) void attn_kernel(
    const bf16_t* __restrict__ Qh, const bf16_t* __restrict__ Kh,
    const bf16_t* __restrict__ Vh, const float* __restrict__ mask,
    bf16_t* __restrict__ ctx)
{
  __shared__ __align__(16) bf16_t Klds[64 * 136];     // [kk][d], pad 136
  __shared__ __align__(16) bf16_t Vt[128 * 72];       // [d][kk^swz], pad 72
  __shared__ __align__(16) bf16_t Plds[4][32 * 72];   // per-wave P bounce

  const int t = threadIdx.x;
  const int lane = t & 63;
  const int wid  = t >> 6;
  const int bh = blockIdx.y;
  const int b  = bh >> 4;
  const int h  = bh & 15;
  const int q0 = blockIdx.x * 128 + wid * 32;

  const size_t headoff = (size_t)bh * S_ * HD_;
  const bf16_t* Qb = Qh + headoff + (size_t)q0 * HD_;
  const bf16_t* Kg = Kh + headoff;
  const bf16_t* Vg = Vh + headoff;

  // Q fragments held in registers: A-frag row = lane&15, k = (lane>>4)*8+j
  bf16x8 qf[2][4];
  #pragma unroll
  for (int mh = 0; mh < 2; ++mh)
    #pragma unroll
    for (int ks = 0; ks < 4; ++ks)
      qf[mh][ks] = *(const bf16x8*)&Qb[(size_t)(mh * 16 + (lane & 15)) * HD_ + ks * 32 + (lane >> 4) * 8];

  f32x4 acc[2][8] = {};
  float m_run[2][4], l_run[2][4];
  #pragma unroll
  for (int mh = 0; mh < 2; ++mh)
    #pragma unroll
    for (int r = 0; r < 4; ++r) { m_run[mh][r] = -INFINITY; l_run[mh][r] = 0.0f; }

  bf16_t* Pw = &Plds[wid][0];
  const int srow  = t >> 4;          // 0..15
  const int scol8 = (t & 15) * 8;    // 0..120

  #pragma unroll 1
  for (int it = 0; it < S_ / KVB; ++it) {
    const int kv0 = it * KVB;
    __syncthreads();
    #pragma unroll
    for (int i = 0; i < 4; ++i) {
      const int rr = srow + i * 16;               // kv row 0..63
      const bf16x8 kvv = *(const bf16x8*)&Kg[(size_t)(kv0 + rr) * HD_ + scol8];
      *(bf16x8*)&Klds[rr * 136 + scol8] = kvv;
      const bf16x8 vvv = *(const bf16x8*)&Vg[(size_t)(kv0 + rr) * HD_ + scol8];
      #pragma unroll
      for (int j = 0; j < 8; ++j)
        Vt[VT_IDX(scol8 + j, rr)] = vvv[j];       // transpose, swizzled
    }
    __syncthreads();

    // S = Q K^T  (A=Q, B=K rows as B^T)
    f32x4 sacc[2][4] = {};
    #pragma unroll
    for (int ns = 0; ns < 4; ++ns) {
      #pragma unroll
      for (int ks = 0; ks < 4; ++ks) {
        const bf16x8 kf = *(const bf16x8*)&Klds[(ns * 16 + (lane & 15)) * 136 + ks * 32 + (lane >> 4) * 8];
        sacc[0][ns] = mfma_16x16x32(qf[0][ks], kf, sacc[0][ns]);
        sacc[1][ns] = mfma_16x16x32(qf[1][ks], kf, sacc[1][ns]);
      }
    }

    float msk[4];
    #pragma unroll
    for (int ns = 0; ns < 4; ++ns)
      msk[ns] = mask[(size_t)b * S_ + kv0 + ns * 16 + (lane & 15)];

    // online softmax. D-frag: col(kk) = lane&15, row(q) = (lane>>4)*4 + r
    #pragma unroll
    for (int mh = 0; mh < 2; ++mh) {
      float sv[4][4];
      float tmax[4] = {-INFINITY, -INFINITY, -INFINITY, -INFINITY};
      #pragma unroll
      for (int ns = 0; ns < 4; ++ns)
        #pragma unroll
        for (int r = 0; r < 4; ++r) {
          sv[ns][r] = sacc[mh][ns][r] * SCALE_F + msk[ns];
          tmax[r] = fmaxf(tmax[r], sv[ns][r]);
        }
      #pragma unroll
      for (int off = 1; off < 16; off <<= 1)
        #pragma unroll
        for (int r = 0; r < 4; ++r)
          tmax[r] = fmaxf(tmax[r], __shfl_xor(tmax[r], off));

      float scl[4], rsum[4];
      #pragma unroll
      for (int r = 0; r < 4; ++r) {
        const float mnew = fmaxf(m_run[mh][r], tmax[r]);
        scl[r] = __expf(m_run[mh][r] - mnew);
        m_run[mh][r] = mnew;
        rsum[r] = 0.0f;
      }
      #pragma unroll
      for (int ns = 0; ns < 4; ++ns)
        #pragma unroll
        for (int r = 0; r < 4; ++r) {
          const float p = __expf(sv[ns][r] - m_run[mh][r]);
          rsum[r] += p;
          Pw[(mh * 16 + (lane >> 4) * 4 + r) * 72 + ns * 16 + (lane & 15)] = (bf16_t)p;
        }
      #pragma unroll
      for (int off = 1; off < 16; off <<= 1)
        #pragma unroll
        for (int r = 0; r < 4; ++r)
          rsum[r] += __shfl_xor(rsum[r], off);
      #pragma unroll
      for (int r = 0; r < 4; ++r)
        l_run[mh][r] = l_run[mh][r] * scl[r] + rsum[r];
      #pragma unroll
      for (int ds = 0; ds < 8; ++ds)
        #pragma unroll
        for (int r = 0; r < 4; ++r)
          acc[mh][ds][r] *= scl[r];
    }

    // ctx += P * V   (A=P from LDS bounce, B=V^T)
    bf16x8 pf[2][2];
    #pragma unroll
    for (int mh = 0; mh < 2; ++mh)
      #pragma unroll
      for (int k2 = 0; k2 < 2; ++k2)
        pf[mh][k2] = *(const bf16x8*)&Pw[(mh * 16 + (lane & 15)) * 72 + k2 * 32 + (lane >> 4) * 8];

    #pragma unroll
    for (int ds = 0; ds < 8; ++ds) {
      const int d = ds * 16 + (lane & 15);
      const bf16x8 vf0 = *(const bf16x8*)&Vt[VT_IDX(d, (lane >> 4) * 8)];
      const bf16x8 vf1 = *(const bf16x8*)&Vt[VT_IDX(d, 32 + (lane >> 4) * 8)];
      #pragma unroll
      for (int mh = 0; mh < 2; ++mh) {
        acc[mh][ds] = mfma_16x16x32(pf[mh][0], vf0, acc[mh][ds]);
        acc[mh][ds] = mfma_16x16x32(pf[mh][1], vf1, acc[mh][ds]);
      }
    }
  }

  // normalize + write ctx back in [B,S,H] (bf16) for the O-projection GEMM
  #pragma unroll
  for (int mh = 0; mh < 2; ++mh)
    #pragma unroll
    for (int ds = 0; ds < 8; ++ds)
      #pragma unroll
      for (int r = 0; r < 4; ++r) {
        const int q = q0 + mh * 16 + (lane >> 4) * 4 + r;
        const int d = ds * 16 + (lane & 15);
        ctx[((size_t)(b * S_ + q)) * H_ + h * HD_ + d] =
            (bf16_t)(acc[mh][ds][r] / l_run[mh][r]);
      }
}

// ---------------------------------------------------------------------- host
extern "C" void kernel_launch(void* const* d_in, const int* in_sizes, int n_in,
                              void* d_out, int out_size, void* d_ws, size_t ws_size,
                              hipStream_t stream) {
  (void)in_sizes; (void)n_in; (void)out_size; (void)ws_size;
  const float* x    = (const float*)d_in[0];
  const float* mask = (const float*)d_in[1];
  const float* Wq   = (const float*)d_in[2];
  const float* bq   = (const float*)d_in[3];
  const float* Wk   = (const float*)d_in[4];
  const float* bk   = (const float*)d_in[5];
  const float* Wv   = (const float*)d_in[6];
  const float* bv   = (const float*)d_in[7];
  const float* Wo   = (const float*)d_in[8];
  const float* bo   = (const float*)d_in[9];
  float* out = (float*)d_out;

  const size_t nX = (size_t)MM_ * H_;   // 8,388,608
  const size_t nW = (size_t)H_ * H_;    // 4,194,304

  // ws layout (bf16): x | Wq Wk Wv Wo | Q K V (head-major) | ctx  = 96 MiB
  bf16_t* xbf = (bf16_t*)d_ws;
  bf16_t* wqb = xbf + nX;
  bf16_t* wkb = wqb + nW;
  bf16_t* wvb = wkb + nW;
  bf16_t* wob = wvb + nW;
  bf16_t* qh  = wob + nW;
  bf16_t* kh  = qh + nX;
  bf16_t* vh  = kh + nX;
  bf16_t* cxb = vh + nX;

  cvt_f32_bf16<<<2048, 256, 0, stream>>>(x,  xbf, (int)(nX / 8));
  cvt_f32_bf16<<<1024, 256, 0, stream>>>(Wq, wqb, (int)(nW / 8));
  cvt_f32_bf16<<<1024, 256, 0, stream>>>(Wk, wkb, (int)(nW / 8));
  cvt_f32_bf16<<<1024, 256, 0, stream>>>(Wv, wvb, (int)(nW / 8));
  cvt_f32_bf16<<<1024, 256, 0, stream>>>(Wo, wob, (int)(nW / 8));

  gemm_bt<0><<<dim3(MM_ / 128, 48), 256, 0, stream>>>(
      xbf, wqb, wkb, wvb, bq, bk, bv, qh, kh, vh, nullptr);

  attn_kernel<<<dim3(S_ / 128, B_ * NH_), 256, 0, stream>>>(qh, kh, vh, mask, cxb);

  gemm_bt<1><<<dim3(MM_ / 128, H_ / 128), 256, 0, stream>>>(
      cxb, wob, nullptr, nullptr, bo, nullptr, nullptr, nullptr, nullptr, nullptr, out);
}